// Round 2
// baseline (1459.221 us; speedup 1.0000x reference)
//
#include <hip/hip_runtime.h>
#include <cstdint>
#include <cstddef>

// ---------------------------------------------------------------------------
// GraphSAGE (4x SAGEConv + ReLU + log_softmax) on MI355X.
//   - CSR build (histogram + scan + scatter) once per launch
//   - gather-style mean aggregation (no fp32 atomics)
//   - fused dual-GEMM  out = A1@W1 + A2@W2 + b (+ReLU)
//   - transform-before-aggregate on layers 3/4 (aggregation is linear)
// Storage dtype of intermediates is chosen at launch from ws_size:
//   fp32 plan needs ~349 MiB, bf16 plan ~179 MiB. Compute is fp32 either way.
// ---------------------------------------------------------------------------

// ---------------- bf16 <-> f32 helpers ----------------

__device__ __forceinline__ float b2f(unsigned short u) {
    union { unsigned int i; float f; } x; x.i = ((unsigned int)u) << 16; return x.f;
}
__device__ __forceinline__ unsigned short f2b(float f) {
    union { float f; unsigned int i; } x; x.f = f;
    unsigned int r = x.i + 0x7FFFu + ((x.i >> 16) & 1u);  // round-nearest-even
    return (unsigned short)(r >> 16);
}

// generic vector load/store: T in {float, unsigned short(bf16)}, V in {1,2,4}
template <typename T, int V>
__device__ __forceinline__ void loadv(const T* p, float* o) {
    if constexpr (sizeof(T) == 4) {
        const float* q = (const float*)p;
        if constexpr (V == 1) { o[0] = q[0]; }
        else if constexpr (V == 2) { float2 t = *(const float2*)q; o[0] = t.x; o[1] = t.y; }
        else { float4 t = *(const float4*)q; o[0] = t.x; o[1] = t.y; o[2] = t.z; o[3] = t.w; }
    } else {
        const unsigned short* q = (const unsigned short*)p;
        if constexpr (V == 1) { o[0] = b2f(q[0]); }
        else if constexpr (V == 2) { ushort2 t = *(const ushort2*)q; o[0] = b2f(t.x); o[1] = b2f(t.y); }
        else { ushort4 t = *(const ushort4*)q;
               o[0] = b2f(t.x); o[1] = b2f(t.y); o[2] = b2f(t.z); o[3] = b2f(t.w); }
    }
}
template <typename T, int V>
__device__ __forceinline__ void storev(T* p, const float* v) {
    if constexpr (sizeof(T) == 4) {
        float* q = (float*)p;
        if constexpr (V == 1) { q[0] = v[0]; }
        else if constexpr (V == 2) { *(float2*)q = make_float2(v[0], v[1]); }
        else { *(float4*)q = make_float4(v[0], v[1], v[2], v[3]); }
    } else {
        unsigned short* q = (unsigned short*)p;
        if constexpr (V == 1) { q[0] = f2b(v[0]); }
        else if constexpr (V == 2) { ushort2 t; t.x = f2b(v[0]); t.y = f2b(v[1]); *(ushort2*)q = t; }
        else { ushort4 t; t.x = f2b(v[0]); t.y = f2b(v[1]); t.z = f2b(v[2]); t.w = f2b(v[3]);
               *(ushort4*)q = t; }
    }
}

// ---------------- CSR construction ----------------

__global__ void hist_kernel(const int* __restrict__ dst, int E, int* __restrict__ deg) {
    int e = blockIdx.x * 256 + threadIdx.x;
    if (e < E) atomicAdd(&deg[dst[e]], 1);
}

__global__ void scan_blocks(const int* __restrict__ deg, int Nn,
                            int* __restrict__ rp, int* __restrict__ bsum) {
    __shared__ int lds[256];
    int i = blockIdx.x * 256 + threadIdx.x;
    int v = (i < Nn) ? deg[i] : 0;
    lds[threadIdx.x] = v;
    __syncthreads();
    for (int off = 1; off < 256; off <<= 1) {
        int t = (threadIdx.x >= (unsigned)off) ? lds[threadIdx.x - off] : 0;
        __syncthreads();
        lds[threadIdx.x] += t;
        __syncthreads();
    }
    if (i < Nn) rp[i] = lds[threadIdx.x] - v;
    if (threadIdx.x == 255) bsum[blockIdx.x] = lds[255];
}

__global__ void scan_sums(int* __restrict__ bsum, int nb) {
    __shared__ int lds[1024];
    int t = threadIdx.x;
    int v = (t < nb) ? bsum[t] : 0;
    lds[t] = v;
    __syncthreads();
    for (int off = 1; off < 1024; off <<= 1) {
        int u = (t >= off) ? lds[t - off] : 0;
        __syncthreads();
        lds[t] += u;
        __syncthreads();
    }
    if (t < nb) bsum[t] = lds[t] - v;
}

__global__ void finalize_rp(int* __restrict__ rp, const int* __restrict__ bsum,
                            int Nn, int E, int* __restrict__ pos) {
    int i = blockIdx.x * 256 + threadIdx.x;
    if (i < Nn) {
        int v = rp[i] + bsum[blockIdx.x];
        rp[i] = v;
        pos[i] = v;
    }
    if (i == 0) rp[Nn] = E;
}

__global__ void scatter_kernel(const int* __restrict__ src, const int* __restrict__ dst,
                               int E, int* __restrict__ pos, int* __restrict__ ssrc) {
    int e = blockIdx.x * 256 + threadIdx.x;
    if (e < E) {
        int p = atomicAdd(&pos[dst[e]], 1);
        ssrc[p] = src[e];
    }
}

// ---------------- mean aggregation (one wave per node) ----------------

template <typename TF, typename TO, int VPT, bool ADD, bool RELU, bool LSM>
__global__ __launch_bounds__(256) void agg_kernel(
    const TF* __restrict__ feat, int ldF, int offF,
    const TF* __restrict__ addB, int ldA, int offA,
    TO* __restrict__ outp, int ldO, int offO,
    const int* __restrict__ rp, const int* __restrict__ ssrc, int Nn)
{
    int wid  = threadIdx.x >> 6;
    int lane = threadIdx.x & 63;
    int n = blockIdx.x * 4 + wid;
    if (n >= Nn) return;

    int s = rp[n], e = rp[n + 1];
    float acc[VPT];
#pragma unroll
    for (int j = 0; j < VPT; ++j) acc[j] = 0.f;

    float t[VPT];
    for (int k = s; k < e; ++k) {
        int sc = ssrc[k];
        loadv<TF, VPT>(feat + (size_t)sc * ldF + offF + lane * VPT, t);
#pragma unroll
        for (int j = 0; j < VPT; ++j) acc[j] += t[j];
    }

    int cnt = e - s;
    float inv = 1.0f / (float)(cnt > 0 ? cnt : 1);
#pragma unroll
    for (int j = 0; j < VPT; ++j) acc[j] *= inv;

    if constexpr (ADD) {
        loadv<TF, VPT>(addB + (size_t)n * ldA + offA + lane * VPT, t);
#pragma unroll
        for (int j = 0; j < VPT; ++j) acc[j] += t[j];
    }

    if constexpr (RELU) {
#pragma unroll
        for (int j = 0; j < VPT; ++j) acc[j] = fmaxf(acc[j], 0.f);
    }

    TO* o = outp + (size_t)n * ldO + offO + lane * VPT;
    if constexpr (LSM) {
        // D == 64, VPT == 1: full wave holds one row
        float v = acc[0];
        float m = v;
#pragma unroll
        for (int off = 32; off > 0; off >>= 1) m = fmaxf(m, __shfl_xor(m, off));
        float ex = expf(v - m);
        float ssum = ex;
#pragma unroll
        for (int off = 32; off > 0; off >>= 1) ssum += __shfl_xor(ssum, off);
        float r = v - m - logf(ssum);
        storev<TO, 1>(o, &r);
    } else {
        storev<TO, VPT>(o, acc);
    }
}

// ---------------- tiled fp32 GEMM ----------------
// out[row, colOff+col] = (A1@W1 [+ A2@W2])[row,col] + bias[col]  (+ReLU)
// A row-major [M,K] (ld == K), W row-major [K,Nout] fp32. 64x64 tile, BK=32.

template <typename TA1, typename TA2, typename TO, bool DUAL, bool RELU>
__global__ __launch_bounds__(256) void gemm_kernel(
    const TA1* __restrict__ A1, const float* __restrict__ W1,
    const TA2* __restrict__ A2, const float* __restrict__ W2,
    const float* __restrict__ bias,
    TO* __restrict__ outp, int ldOut, int colOff,
    int M, int Nout, int K)
{
    constexpr int NBUF = DUAL ? 2 : 1;
    __shared__ float sA[NBUF][32][68];  // [k][row], padded
    __shared__ float sW[NBUF][32][64];  // [k][col]

    int tid = threadIdx.x;
    int tx = tid & 15, ty = tid >> 4;
    int row0 = blockIdx.x * 64;
    int nB   = blockIdx.y * 64;

    float acc[4][4] = {{0.f}};

    for (int k0 = 0; k0 < K; k0 += 32) {
        // stage A (64 rows x 32 k), transposed into sA[k][row]
#pragma unroll
        for (int it = 0; it < 2; ++it) {
            int idx = tid + it * 256;          // 0..511 quads
            int r = idx >> 3;                  // 0..63
            int c = (idx & 7) << 2;            // 0..28
            int grow = row0 + r;
            float v1[4] = {0.f, 0.f, 0.f, 0.f};
            float v2[4] = {0.f, 0.f, 0.f, 0.f};
            if (grow < M) {
                loadv<TA1, 4>(A1 + (size_t)grow * K + k0 + c, v1);
                if constexpr (DUAL) loadv<TA2, 4>(A2 + (size_t)grow * K + k0 + c, v2);
            }
#pragma unroll
            for (int j = 0; j < 4; ++j) sA[0][c + j][r] = v1[j];
            if constexpr (DUAL) {
#pragma unroll
                for (int j = 0; j < 4; ++j) sA[1][c + j][r] = v2[j];
            }
        }
        // stage W (32 k x 64 cols)
#pragma unroll
        for (int it = 0; it < 2; ++it) {
            int idx = tid + it * 256;
            int kk = idx >> 4;                 // 0..31
            int n  = (idx & 15) << 2;          // 0..60
            float4 w1 = *(const float4*)(W1 + (size_t)(k0 + kk) * Nout + nB + n);
            *(float4*)&sW[0][kk][n] = w1;
            if constexpr (DUAL) {
                float4 w2 = *(const float4*)(W2 + (size_t)(k0 + kk) * Nout + nB + n);
                *(float4*)&sW[1][kk][n] = w2;
            }
        }
        __syncthreads();

#pragma unroll
        for (int k = 0; k < 32; ++k) {
            float4 a = *(const float4*)&sA[0][k][ty * 4];
            float4 wv4 = *(const float4*)&sW[0][k][tx * 4];
            float av[4] = {a.x, a.y, a.z, a.w};
            float wv[4] = {wv4.x, wv4.y, wv4.z, wv4.w};
#pragma unroll
            for (int i = 0; i < 4; ++i)
#pragma unroll
                for (int j = 0; j < 4; ++j) acc[i][j] += av[i] * wv[j];
            if constexpr (DUAL) {
                float4 a2 = *(const float4*)&sA[1][k][ty * 4];
                float4 w24 = *(const float4*)&sW[1][k][tx * 4];
                float av2[4] = {a2.x, a2.y, a2.z, a2.w};
                float wv2[4] = {w24.x, w24.y, w24.z, w24.w};
#pragma unroll
                for (int i = 0; i < 4; ++i)
#pragma unroll
                    for (int j = 0; j < 4; ++j) acc[i][j] += av2[i] * wv2[j];
            }
        }
        __syncthreads();
    }

    float bv[4] = {0.f, 0.f, 0.f, 0.f};
    if (bias) loadv<float, 4>(bias + nB + tx * 4, bv);
#pragma unroll
    for (int i = 0; i < 4; ++i) {
        int row = row0 + ty * 4 + i;
        if (row < M) {
            float o[4];
#pragma unroll
            for (int j = 0; j < 4; ++j) {
                o[j] = acc[i][j] + bv[j];
                if constexpr (RELU) o[j] = fmaxf(o[j], 0.f);
            }
            storev<TO, 4>(outp + (size_t)row * ldOut + colOff + nB + tx * 4, o);
        }
    }
}

// ---------------- templated pipeline over storage type T ----------------

template <typename T>
static void run_pipeline(const float* x, const int* src, const int* dst,
                         int N, int E,
                         const float* Wl1, const float* Wr1, const float* b1,
                         const float* Wl2, const float* Wr2, const float* b2,
                         const float* Wl3, const float* Wr3, const float* b3,
                         const float* Wl4, const float* Wr4, const float* b4,
                         float* outp, char* w, hipStream_t stream)
{
    auto alloc = [&](size_t bytes) -> char* {
        char* p = w;
        w += (bytes + 255) & ~(size_t)255;
        return p;
    };
    const int nb = (N + 255) / 256;
    int* deg  = (int*)alloc((size_t)N * 4);
    int* rp   = (int*)alloc((size_t)(N + 1) * 4);
    int* pos  = (int*)alloc((size_t)N * 4);
    int* bsum = (int*)alloc((size_t)nb * 4);
    int* ssrc = (int*)alloc((size_t)E * 4);
    T* mean1 = (T*)alloc((size_t)N * 128 * sizeof(T));  // reused as t3r3
    T* h1    = (T*)alloc((size_t)N * 256 * sizeof(T));  // reused: h3 + t4r4
    T* agg2  = (T*)alloc((size_t)N * 256 * sizeof(T));
    T* h2    = (T*)alloc((size_t)N * 256 * sizeof(T));
    T* t3r3 = mean1;
    T* h3   = h1;                       // [N,64]
    T* t4r4 = h1 + (size_t)N * 64;      // [N,128]

    const int ge = (E + 255) / 256;
    const int ga = (N + 3) / 4;
    dim3 blk(256);

    // ---- CSR build ----
    hipMemsetAsync(deg, 0, (size_t)N * 4, stream);
    hist_kernel<<<ge, blk, 0, stream>>>(dst, E, deg);
    scan_blocks<<<nb, blk, 0, stream>>>(deg, N, rp, bsum);
    scan_sums<<<1, 1024, 0, stream>>>(bsum, nb);
    finalize_rp<<<nb, blk, 0, stream>>>(rp, bsum, N, E, pos);
    scatter_kernel<<<ge, blk, 0, stream>>>(src, dst, E, pos, ssrc);

    // ---- layer 1: h1 = relu(mean(x)@Wl1 + x@Wr1 + b1) ----
    agg_kernel<float, T, 2, false, false, false><<<ga, blk, 0, stream>>>(
        x, 128, 0, nullptr, 0, 0, mean1, 128, 0, rp, ssrc, N);
    dim3 g1((N + 63) / 64, 4);
    gemm_kernel<T, float, T, true, true><<<g1, blk, 0, stream>>>(
        mean1, Wl1, x, Wr1, b1, h1, 256, 0, N, 256, 128);

    // ---- layer 2: h2 = relu(mean(h1)@Wl2 + h1@Wr2 + b2) ----
    agg_kernel<T, T, 4, false, false, false><<<ga, blk, 0, stream>>>(
        h1, 256, 0, nullptr, 0, 0, agg2, 256, 0, rp, ssrc, N);
    gemm_kernel<T, T, T, true, true><<<g1, blk, 0, stream>>>(
        agg2, Wl2, h1, Wr2, b2, h2, 256, 0, N, 256, 256);

    // ---- layer 3 (transform-first): t3 = h2@Wl3, r3 = h2@Wr3 + b3 ----
    dim3 g3((N + 63) / 64, 1);
    gemm_kernel<T, float, T, false, false><<<g3, blk, 0, stream>>>(
        h2, Wl3, nullptr, nullptr, nullptr, t3r3, 128, 0, N, 64, 256);
    gemm_kernel<T, float, T, false, false><<<g3, blk, 0, stream>>>(
        h2, Wr3, nullptr, nullptr, b3, t3r3, 128, 64, N, 64, 256);
    // h3 = relu(mean(t3) + r3)
    agg_kernel<T, T, 1, true, true, false><<<ga, blk, 0, stream>>>(
        t3r3, 128, 0, t3r3, 128, 64, h3, 64, 0, rp, ssrc, N);

    // ---- layer 4 (transform-first): t4 = h3@Wl4, r4 = h3@Wr4 + b4 ----
    gemm_kernel<T, float, T, false, false><<<g3, blk, 0, stream>>>(
        h3, Wl4, nullptr, nullptr, nullptr, t4r4, 128, 0, N, 64, 64);
    gemm_kernel<T, float, T, false, false><<<g3, blk, 0, stream>>>(
        h3, Wr4, nullptr, nullptr, b4, t4r4, 128, 64, N, 64, 64);
    // out = log_softmax(mean(t4) + r4)
    agg_kernel<T, float, 1, true, false, true><<<ga, blk, 0, stream>>>(
        t4r4, 128, 0, t4r4, 128, 64, outp, 64, 0, rp, ssrc, N);
}

// ---------------- launch ----------------

extern "C" void kernel_launch(void* const* d_in, const int* in_sizes, int n_in,
                              void* d_out, int out_size, void* d_ws, size_t ws_size,
                              hipStream_t stream)
{
    const float* x   = (const float*)d_in[0];
    const int*   ei  = (const int*)d_in[1];
    const float* Wl1 = (const float*)d_in[2];
    const float* Wr1 = (const float*)d_in[3];
    const float* b1  = (const float*)d_in[4];
    const float* Wl2 = (const float*)d_in[5];
    const float* Wr2 = (const float*)d_in[6];
    const float* b2  = (const float*)d_in[7];
    const float* Wl3 = (const float*)d_in[8];
    const float* Wr3 = (const float*)d_in[9];
    const float* b3  = (const float*)d_in[10];
    const float* Wl4 = (const float*)d_in[11];
    const float* Wr4 = (const float*)d_in[12];
    const float* b4  = (const float*)d_in[13];
    float* outp = (float*)d_out;

    const int N = in_sizes[0] / 128;
    const int E = in_sizes[1] / 2;
    const int* src = ei;
    const int* dst = ei + E;

    auto a256 = [](size_t b) { return (b + 255) & ~(size_t)255; };
    const int nb = (N + 255) / 256;
    size_t csr = a256((size_t)N * 4) * 2 + a256((size_t)(N + 1) * 4) +
                 a256((size_t)nb * 4) + a256((size_t)E * 4);
    size_t need_f32 = csr + a256((size_t)N * 128 * 4) + 3 * a256((size_t)N * 256 * 4);

    if (ws_size >= need_f32) {
        run_pipeline<float>(x, src, dst, N, E, Wl1, Wr1, b1, Wl2, Wr2, b2,
                            Wl3, Wr3, b3, Wl4, Wr4, b4, outp, (char*)d_ws, stream);
    } else {
        run_pipeline<unsigned short>(x, src, dst, N, E, Wl1, Wr1, b1, Wl2, Wr2, b2,
                                     Wl3, Wr3, b3, Wl4, Wr4, b4, outp, (char*)d_ws, stream);
    }
}

// Round 3
// 737.572 us; speedup vs baseline: 1.9784x; 1.9784x over previous
//
#include <hip/hip_runtime.h>
#include <cstdint>
#include <cstddef>

// ---------------------------------------------------------------------------
// GraphSAGE (4x SAGEConv + ReLU + log_softmax) on MI355X — round 3.
//   - CSR build once per launch (histogram + scan + scatter)
//   - gather-style mean aggregation, 16B/lane bf16 loads, multi-node/wave
//   - bf16 MFMA GEMM (16x16x32), BM=256 BN=64 BK=64, transposed bf16 weights
//   - dual-GEMM via two K-loop passes into same accumulators
//   - layers 3/4: transform-first + [Wl|Wr] column-concat single GEMM
// All intermediate storage bf16; accumulation fp32.
// ---------------------------------------------------------------------------

typedef short s16x8 __attribute__((ext_vector_type(8)));
typedef float f32x4 __attribute__((ext_vector_type(4)));
typedef unsigned short u16;
typedef unsigned short u16x8 __attribute__((ext_vector_type(8)));

__device__ __forceinline__ float b2f(u16 u) {
    union { unsigned int i; float f; } x; x.i = ((unsigned int)u) << 16; return x.f;
}
__device__ __forceinline__ u16 f2b(float f) {
    union { float f; unsigned int i; } x; x.f = f;
    unsigned int r = x.i + 0x7FFFu + ((x.i >> 16) & 1u);  // RNE
    return (u16)(r >> 16);
}

// ---------------- CSR construction ----------------

__global__ void hist_kernel(const int* __restrict__ dst, int E, int* __restrict__ deg) {
    int e = blockIdx.x * 256 + threadIdx.x;
    if (e < E) atomicAdd(&deg[dst[e]], 1);
}

__global__ void scan_blocks(const int* __restrict__ deg, int Nn,
                            int* __restrict__ rp, int* __restrict__ bsum) {
    __shared__ int lds[256];
    int i = blockIdx.x * 256 + threadIdx.x;
    int v = (i < Nn) ? deg[i] : 0;
    lds[threadIdx.x] = v;
    __syncthreads();
    for (int off = 1; off < 256; off <<= 1) {
        int t = (threadIdx.x >= (unsigned)off) ? lds[threadIdx.x - off] : 0;
        __syncthreads();
        lds[threadIdx.x] += t;
        __syncthreads();
    }
    if (i < Nn) rp[i] = lds[threadIdx.x] - v;
    if (threadIdx.x == 255) bsum[blockIdx.x] = lds[255];
}

__global__ void scan_sums(int* __restrict__ bsum, int nb) {
    __shared__ int lds[1024];
    int t = threadIdx.x;
    int v = (t < nb) ? bsum[t] : 0;
    lds[t] = v;
    __syncthreads();
    for (int off = 1; off < 1024; off <<= 1) {
        int u = (t >= off) ? lds[t - off] : 0;
        __syncthreads();
        lds[t] += u;
        __syncthreads();
    }
    if (t < nb) bsum[t] = lds[t] - v;
}

__global__ void finalize_rp(int* __restrict__ rp, const int* __restrict__ bsum,
                            int Nn, int E, int* __restrict__ pos) {
    int i = blockIdx.x * 256 + threadIdx.x;
    if (i < Nn) {
        int v = rp[i] + bsum[blockIdx.x];
        rp[i] = v;
        pos[i] = v;
    }
    if (i == 0) rp[Nn] = E;
}

__global__ void scatter_kernel(const int* __restrict__ src, const int* __restrict__ dst,
                               int E, int* __restrict__ pos, int* __restrict__ ssrc) {
    int e = blockIdx.x * 256 + threadIdx.x;
    if (e < E) {
        int p = atomicAdd(&pos[dst[e]], 1);
        ssrc[p] = src[e];
    }
}

// ---------------- prep kernels ----------------

// x fp32 -> bf16, 8 elems/thread
__global__ void cvt_kernel(const float* __restrict__ in, u16* __restrict__ out, long total) {
    long i = ((long)blockIdx.x * 256 + threadIdx.x) * 8;
    if (i + 8 > total) return;
    float4 a = *(const float4*)(in + i);
    float4 b = *(const float4*)(in + i + 4);
    u16x8 v;
    v[0] = f2b(a.x); v[1] = f2b(a.y); v[2] = f2b(a.z); v[3] = f2b(a.w);
    v[4] = f2b(b.x); v[5] = f2b(b.y); v[6] = f2b(b.z); v[7] = f2b(b.w);
    *(u16x8*)(out + i) = v;
}

// W [K][Nout] fp32 -> Wt [Nout+rowOff][K] bf16 (transpose + convert)
__global__ void wprep_kernel(const float* __restrict__ W, int K, int Nout,
                             u16* __restrict__ Wt, int rowOff) {
    int idx = blockIdx.x * 256 + threadIdx.x;
    if (idx >= K * Nout) return;
    int k = idx / Nout, n = idx - k * Nout;
    Wt[(size_t)(n + rowOff) * K + k] = f2b(W[idx]);
}

// bias concat: b3c = [0(64) | b3], b4c = [0(64) | b4]
__global__ void bprep_kernel(const float* __restrict__ b3, const float* __restrict__ b4,
                             float* __restrict__ b3c, float* __restrict__ b4c) {
    int i = threadIdx.x;  // 0..127
    b3c[i] = (i < 64) ? 0.f : b3[i - 64];
    b4c[i] = (i < 64) ? 0.f : b4[i - 64];
}

// ---------------- mean aggregation ----------------
// out[n,:] = mean over nbrs of feat[s, offF:offF+LPN*8]  (bf16 in)
// LPN lanes per node, each lane 8 bf16 (16B). Optional +addB, ReLU, log_softmax.

template <int LPN, bool ADD, bool RELU, bool LSM>
__global__ __launch_bounds__(256) void agg_kernel(
    const u16* __restrict__ feat, int ldF, int offF,
    const u16* __restrict__ addB, int ldA, int offA,
    void* __restrict__ outp, int ldO,
    const int* __restrict__ rp, const int* __restrict__ ssrc, int Nn)
{
    constexpr int NPW = 64 / LPN;  // nodes per wave
    int lane = threadIdx.x & 63;
    int wid  = threadIdx.x >> 6;
    int sub  = lane / LPN;
    int sl   = lane % LPN;
    int n = (blockIdx.x * 4 + wid) * NPW + sub;
    if (n >= Nn) return;

    int s = rp[n], e = rp[n + 1];
    float acc[8] = {0.f, 0.f, 0.f, 0.f, 0.f, 0.f, 0.f, 0.f};
    const size_t co = (size_t)offF + (size_t)sl * 8;

    for (int k = s; k < e; ++k) {
        int sc = ssrc[k];
        u16x8 v = *(const u16x8*)(feat + (size_t)sc * ldF + co);
#pragma unroll
        for (int j = 0; j < 8; ++j) acc[j] += b2f(v[j]);
    }

    int cnt = e - s;
    float inv = 1.0f / (float)(cnt > 0 ? cnt : 1);
#pragma unroll
    for (int j = 0; j < 8; ++j) acc[j] *= inv;

    if constexpr (ADD) {
        u16x8 v = *(const u16x8*)(addB + (size_t)n * ldA + offA + (size_t)sl * 8);
#pragma unroll
        for (int j = 0; j < 8; ++j) acc[j] += b2f(v[j]);
    }
    if constexpr (RELU) {
#pragma unroll
        for (int j = 0; j < 8; ++j) acc[j] = fmaxf(acc[j], 0.f);
    }

    if constexpr (LSM) {
        // LPN == 8: one row = 8 lanes x 8 elems
        float m = acc[0];
#pragma unroll
        for (int j = 1; j < 8; ++j) m = fmaxf(m, acc[j]);
#pragma unroll
        for (int off = 1; off < 8; off <<= 1) m = fmaxf(m, __shfl_xor(m, off));
        float ss = 0.f;
#pragma unroll
        for (int j = 0; j < 8; ++j) ss += expf(acc[j] - m);
#pragma unroll
        for (int off = 1; off < 8; off <<= 1) ss += __shfl_xor(ss, off);
        float lse = m + logf(ss);
        float* o = (float*)outp + (size_t)n * ldO + (size_t)sl * 8;
        float4 o0 = make_float4(acc[0] - lse, acc[1] - lse, acc[2] - lse, acc[3] - lse);
        float4 o1 = make_float4(acc[4] - lse, acc[5] - lse, acc[6] - lse, acc[7] - lse);
        *(float4*)o = o0;
        *(float4*)(o + 4) = o1;
    } else {
        u16x8 v;
#pragma unroll
        for (int j = 0; j < 8; ++j) v[j] = f2b(acc[j]);
        *(u16x8*)((u16*)outp + (size_t)n * ldO + (size_t)sl * 8) = v;
    }
}

// ---------------- bf16 MFMA GEMM ----------------
// out[row, nB+col] = (A1@Wt1^T [+ A2@Wt2^T])[row,col] + bias[nB+col] (+ReLU), bf16 out.
// A [M][K] bf16 row-major; Wt [Ntot][K] bf16 (pre-transposed weight).
// BM=256, BN=64 (gridDim.y picks col-block), BK=64. 256 thr = 4 waves,
// wave w owns rows [w*64, w*64+64) x all 64 cols: 4x4 fragments of 16x16x32.

template <bool DUAL, bool RELU>
__global__ __launch_bounds__(256) void gemm_mfma(
    const u16* __restrict__ A1, const u16* __restrict__ Wt1, int K1,
    const u16* __restrict__ A2, const u16* __restrict__ Wt2, int K2,
    const float* __restrict__ bias,
    u16* __restrict__ outp, int ldOut, int M)
{
    __shared__ u16 sA[256][72];  // [row][k], pad 64->72 (row stride 144B, 16B-aligned)
    __shared__ u16 sW[64][72];   // [outcol][k]

    const int tid = threadIdx.x;
    const int lane = tid & 63, wid = tid >> 6;
    const int r16 = lane & 15, khalf = lane >> 4;      // khalf 0..3
    const int row0 = blockIdx.x * 256;
    const int nB   = blockIdx.y * 64;

    f32x4 acc[4][4] = {};

#pragma unroll 1
    for (int s = 0; s < (DUAL ? 2 : 1); ++s) {
        const u16* A  = (s == 0) ? A1 : A2;
        const u16* Wt = (s == 0) ? Wt1 : Wt2;
        const int  K  = (s == 0) ? K1 : K2;
        for (int k0 = 0; k0 < K; k0 += 64) {
            // stage A: 256 rows x 64 k  (2048 x 16B / 256 thr = 8 iters)
#pragma unroll
            for (int it = 0; it < 8; ++it) {
                int idx = it * 256 + tid;
                int r = idx >> 3, kq = (idx & 7) * 8;
                int grow = row0 + r;
                s16x8 v = {};
                if (grow < M) v = *(const s16x8*)(A + (size_t)grow * K + k0 + kq);
                *(s16x8*)&sA[r][kq] = v;
            }
            // stage W: 64 rows x 64 k (2 iters)
#pragma unroll
            for (int it = 0; it < 2; ++it) {
                int idx = it * 256 + tid;
                int r = idx >> 3, kq = (idx & 7) * 8;
                s16x8 v = *(const s16x8*)(Wt + (size_t)(nB + r) * K + k0 + kq);
                *(s16x8*)&sW[r][kq] = v;
            }
            __syncthreads();

#pragma unroll
            for (int ks = 0; ks < 2; ++ks) {
                const int kb = ks * 32 + khalf * 8;
                s16x8 af[4], bfr[4];
#pragma unroll
                for (int m = 0; m < 4; ++m)
                    af[m] = *(const s16x8*)&sA[wid * 64 + m * 16 + r16][kb];
#pragma unroll
                for (int nn = 0; nn < 4; ++nn)
                    bfr[nn] = *(const s16x8*)&sW[nn * 16 + r16][kb];
#pragma unroll
                for (int m = 0; m < 4; ++m)
#pragma unroll
                    for (int nn = 0; nn < 4; ++nn)
                        acc[m][nn] = __builtin_amdgcn_mfma_f32_16x16x32_bf16(
                            af[m], bfr[nn], acc[m][nn], 0, 0, 0);
            }
            __syncthreads();
        }
    }

    // epilogue: C/D layout col=lane&15, row=(lane>>4)*4+reg  [m89]
    float bv[4];
#pragma unroll
    for (int nn = 0; nn < 4; ++nn) bv[nn] = bias ? bias[nB + nn * 16 + r16] : 0.f;
#pragma unroll
    for (int m = 0; m < 4; ++m) {
#pragma unroll
        for (int r = 0; r < 4; ++r) {
            int grow = row0 + wid * 64 + m * 16 + khalf * 4 + r;
            if (grow < M) {
#pragma unroll
                for (int nn = 0; nn < 4; ++nn) {
                    float v = acc[m][nn][r] + bv[nn];
                    if constexpr (RELU) v = fmaxf(v, 0.f);
                    outp[(size_t)grow * ldOut + nB + nn * 16 + r16] = f2b(v);
                }
            }
        }
    }
}

// ---------------- launch ----------------

extern "C" void kernel_launch(void* const* d_in, const int* in_sizes, int n_in,
                              void* d_out, int out_size, void* d_ws, size_t ws_size,
                              hipStream_t stream)
{
    const float* x   = (const float*)d_in[0];
    const int*   ei  = (const int*)d_in[1];
    const float* Wl1 = (const float*)d_in[2];
    const float* Wr1 = (const float*)d_in[3];
    const float* b1  = (const float*)d_in[4];
    const float* Wl2 = (const float*)d_in[5];
    const float* Wr2 = (const float*)d_in[6];
    const float* b2  = (const float*)d_in[7];
    const float* Wl3 = (const float*)d_in[8];
    const float* Wr3 = (const float*)d_in[9];
    const float* b3  = (const float*)d_in[10];
    const float* Wl4 = (const float*)d_in[11];
    const float* Wr4 = (const float*)d_in[12];
    const float* b4  = (const float*)d_in[13];
    float* outp = (float*)d_out;

    const int N = in_sizes[0] / 128;
    const int E = in_sizes[1] / 2;
    const int* src = ei;
    const int* dst = ei + E;

    char* w = (char*)d_ws;
    auto alloc = [&](size_t bytes) -> char* {
        char* p = w;
        w += (bytes + 255) & ~(size_t)255;
        return p;
    };
    const int nb = (N + 255) / 256;
    int* deg  = (int*)alloc((size_t)N * 4);
    int* rp   = (int*)alloc((size_t)(N + 1) * 4);
    int* pos  = (int*)alloc((size_t)N * 4);
    int* bsum = (int*)alloc((size_t)nb * 4);
    int* ssrc = (int*)alloc((size_t)E * 4);
    u16* mean1 = (u16*)alloc((size_t)N * 128 * 2);   // reused as t3r3 [N,128]
    u16* h1    = (u16*)alloc((size_t)N * 256 * 2);   // reused: h3 [N,64] + t4r4 [N,128]
    u16* agg2  = (u16*)alloc((size_t)N * 256 * 2);
    u16* h2s   = (u16*)alloc((size_t)N * 256 * 2);   // h2; first half doubles as xb
    u16* W1lt = (u16*)alloc((size_t)256 * 128 * 2);
    u16* W1rt = (u16*)alloc((size_t)256 * 128 * 2);
    u16* W2lt = (u16*)alloc((size_t)256 * 256 * 2);
    u16* W2rt = (u16*)alloc((size_t)256 * 256 * 2);
    u16* W3t  = (u16*)alloc((size_t)128 * 256 * 2);
    u16* W4t  = (u16*)alloc((size_t)128 * 64 * 2);
    float* b3c = (float*)alloc(128 * 4);
    float* b4c = (float*)alloc(128 * 4);

    u16* xb   = h2s;                       // [N,128] bf16; dead before h2 written
    u16* h2   = h2s;                       // [N,256]
    u16* t3r3 = mean1;                     // [N,128]
    u16* h3   = h1;                        // [N,64]
    u16* t4r4 = h1 + (size_t)N * 64;       // [N,128]

    const int ge = (E + 255) / 256;
    dim3 blk(256);
    const int gx = (N + 255) / 256;        // GEMM row-blocks (BM=256)

    // ---- CSR build ----
    hipMemsetAsync(deg, 0, (size_t)N * 4, stream);
    hist_kernel<<<ge, blk, 0, stream>>>(dst, E, deg);
    scan_blocks<<<nb, blk, 0, stream>>>(deg, N, rp, bsum);
    scan_sums<<<1, 1024, 0, stream>>>(bsum, nb);
    finalize_rp<<<nb, blk, 0, stream>>>(rp, bsum, N, E, pos);
    scatter_kernel<<<ge, blk, 0, stream>>>(src, dst, E, pos, ssrc);

    // ---- prep: x->bf16, weights transpose+convert, bias concat ----
    long xtot = (long)N * 128;
    cvt_kernel<<<(int)((xtot / 8 + 255) / 256), blk, 0, stream>>>(x, xb, xtot);
    wprep_kernel<<<(128 * 256 + 255) / 256, blk, 0, stream>>>(Wl1, 128, 256, W1lt, 0);
    wprep_kernel<<<(128 * 256 + 255) / 256, blk, 0, stream>>>(Wr1, 128, 256, W1rt, 0);
    wprep_kernel<<<(256 * 256 + 255) / 256, blk, 0, stream>>>(Wl2, 256, 256, W2lt, 0);
    wprep_kernel<<<(256 * 256 + 255) / 256, blk, 0, stream>>>(Wr2, 256, 256, W2rt, 0);
    wprep_kernel<<<(256 * 64 + 255) / 256, blk, 0, stream>>>(Wl3, 256, 64, W3t, 0);
    wprep_kernel<<<(256 * 64 + 255) / 256, blk, 0, stream>>>(Wr3, 256, 64, W3t, 64);
    wprep_kernel<<<(64 * 64 + 255) / 256, blk, 0, stream>>>(Wl4, 64, 64, W4t, 0);
    wprep_kernel<<<(64 * 64 + 255) / 256, blk, 0, stream>>>(Wr4, 64, 64, W4t, 64);
    bprep_kernel<<<1, 128, 0, stream>>>(b3, b4, b3c, b4c);

    // ---- layer 1: h1 = relu(mean(xb)@Wl1 + xb@Wr1 + b1) ----
    agg_kernel<16, false, false, false><<<(N + 15) / 16, blk, 0, stream>>>(
        xb, 128, 0, nullptr, 0, 0, mean1, 128, rp, ssrc, N);
    gemm_mfma<true, true><<<dim3(gx, 4), blk, 0, stream>>>(
        mean1, W1lt, 128, xb, W1rt, 128, b1, h1, 256, N);

    // ---- layer 2: h2 = relu(mean(h1)@Wl2 + h1@Wr2 + b2) ----
    agg_kernel<32, false, false, false><<<(N + 7) / 8, blk, 0, stream>>>(
        h1, 256, 0, nullptr, 0, 0, agg2, 256, rp, ssrc, N);
    gemm_mfma<true, true><<<dim3(gx, 4), blk, 0, stream>>>(
        agg2, W2lt, 256, h1, W2rt, 256, b2, h2, 256, N);

    // ---- layer 3 (transform-first): [t3|r3] = h2@[Wl3|Wr3] + [0|b3] ----
    gemm_mfma<false, false><<<dim3(gx, 2), blk, 0, stream>>>(
        h2, W3t, 256, nullptr, nullptr, 0, b3c, t3r3, 128, N);
    // h3 = relu(mean(t3) + r3)
    agg_kernel<8, true, true, false><<<(N + 31) / 32, blk, 0, stream>>>(
        t3r3, 128, 0, t3r3, 128, 64, h3, 64, rp, ssrc, N);

    // ---- layer 4 (transform-first): [t4|r4] = h3@[Wl4|Wr4] + [0|b4] ----
    gemm_mfma<false, false><<<dim3(gx, 2), blk, 0, stream>>>(
        h3, W4t, 64, nullptr, nullptr, 0, b4c, t4r4, 128, N);
    // out = log_softmax(mean(t4) + r4)
    agg_kernel<8, true, false, true><<<(N + 31) / 32, blk, 0, stream>>>(
        t4r4, 128, 0, t4r4, 128, 64, outp, 64, rp, ssrc, N);
}